// Round 3
// baseline (270.221 us; speedup 1.0000x reference)
//
#include <hip/hip_runtime.h>

// SyntacticGCN on MI355X — fp32 in/out.
// v4: aggregate-then-transform with SCALAR-UNIFORM gather loop.
//   S[n, t*128+d] = sum_{e:tgt=n,t_e=t} g_e * x[src_e, d]   (gather from 25.6MB xb)
//   out[n] = relu(inp[n] + S[n,:] @ Wcat)                    (one K=512 GEMM)
//
// v4 changes (post-mortem of v3: 2x occupancy -> NO change => issue-throughput
// bound, not latency-bound; SQ_LDS_BANK_CONFLICT == E*8 in v2 AND v3 => the
// __shfl ds_bpermutes are on the per-edge critical chain):
//   - one FULL WAVE per row (64 lanes x 1 dword = 256B row). Every per-edge
//     scalar (src, t, gate) is wave-uniform:
//       __shfl -> __builtin_amdgcn_readlane (SGPR, ~4cy, no LDS pipe)
//       gather address is SGPR-based (saddr load, scalar address math)
//       t-branch is a uniform scalar branch (1 body: 2 unpack + 2 FMA)
//   - gate packed into pe.y (fp32 bits) at scatter time; rel in a side array
//     read only by the bias (!bz) fallback. One 8B load/edge.
//   Hot loop: ~6 VALU + ~5 SALU per edge (was ~30 instr + 2 bpermutes).
//
// Pipeline (6 dispatches): memset | conv_hist_k | scan_block_k | scan_add_k |
//   scatter_payload_k | fused_agg_gemm_k.

typedef __attribute__((ext_vector_type(8))) short short8;
typedef __attribute__((ext_vector_type(4))) float floatx4;

#define DIM 128

static __device__ __forceinline__ float bf2f(unsigned int u16bits) {
    unsigned int x = u16bits << 16;
    return __builtin_bit_cast(float, x);
}
static __device__ __forceinline__ unsigned int f2bf(float f) {
    unsigned int x = __builtin_bit_cast(unsigned int, f);
    return (x + 0x7fffu + ((x >> 16) & 1u)) >> 16;
}

// ------- fused: conv+gate (node blocks) | hist | zcheck | weight-convert ---------
__global__ __launch_bounds__(256) void conv_hist_k(
    const float* __restrict__ inp,
    const float* __restrict__ gin,  const float* __restrict__ gout,
    const float* __restrict__ gself, const float* __restrict__ gnorel,
    const float* __restrict__ Vin, const float* __restrict__ Vout,
    const float* __restrict__ Wself, const float* __restrict__ Wnorel,
    unsigned short* __restrict__ xb, float* __restrict__ xg,
    unsigned short* __restrict__ wcatT,
    const int* __restrict__ ei, int* __restrict__ counts,
    const float* __restrict__ b_in, const float* __restrict__ b_out,
    int* __restrict__ bnz, long long nbe,
    int N, int E, int nb_conv, int nb_edge)
{
    int bx = (int)blockIdx.x;
    if (bx >= nb_conv + nb_edge + 256) {
        // weight convert: wcatT[c][k] = bf16(W_t[d][c]), k = t*128+d. 128 blocks.
        int gid = (bx - nb_conv - nb_edge - 256) * 256 + threadIdx.x; // 32768
        int k = gid >> 6;            // 0..511
        int c2 = (gid & 63) * 2;     // 0,2,..,126
        int t = k >> 7, d = k & 127;
        const float* Wt = (t == 0) ? Vin : (t == 1) ? Vout : (t == 2) ? Wself : Wnorel;
        float2 w = *(const float2*)(Wt + (size_t)d * DIM + c2);
        wcatT[(size_t)c2 * 512 + k]       = (unsigned short)f2bf(w.x);
        wcatT[(size_t)(c2 + 1) * 512 + k] = (unsigned short)f2bf(w.y);
        return;
    }
    if (bx >= nb_conv + nb_edge) {
        // sampler: 256 blocks x 256 threads, strided over the bias tables
        long long tid = (long long)(bx - nb_conv - nb_edge) * 256 + threadIdx.x;
        long long stride = nbe / 65536;
        long long i = tid * stride;
        if (i < nbe && (b_in[i] != 0.f || b_out[i] != 0.f)) *bnz = 1;
        return;
    }
    if (bx >= nb_conv) {
        int e = (bx - nb_conv) * 256 + threadIdx.x;
        if (e < E) atomicAdd(&counts[ei[E + e]], 1);
        return;
    }
    int n = bx * 4 + (threadIdx.x >> 6);
    if (n >= N) return;
    int lane = threadIdx.x & 63;

    float2 x = *(const float2*)(inp + (size_t)n * DIM + lane * 2);
    unsigned int o = f2bf(x.x) | (f2bf(x.y) << 16);
    *(unsigned int*)(xb + (size_t)n * DIM + lane * 2) = o;

    float2 g0 = *(const float2*)(gin    + lane * 2);
    float2 g1 = *(const float2*)(gout   + lane * 2);
    float2 g2 = *(const float2*)(gself  + lane * 2);
    float2 g3 = *(const float2*)(gnorel + lane * 2);
    float s0 = x.x * g0.x + x.y * g0.y;
    float s1 = x.x * g1.x + x.y * g1.y;
    float s2 = x.x * g2.x + x.y * g2.y;
    float s3 = x.x * g3.x + x.y * g3.y;
#pragma unroll
    for (int off = 1; off < 64; off <<= 1) {
        s0 += __shfl_xor(s0, off, 64);
        s1 += __shfl_xor(s1, off, 64);
        s2 += __shfl_xor(s2, off, 64);
        s3 += __shfl_xor(s3, off, 64);
    }
    if (lane == 0) *(float4*)(xg + (size_t)n * 4) = make_float4(s0, s1, s2, s3);
}

// ---------------- CSR scan (2 kernels, unchanged) ----------------
__global__ __launch_bounds__(256) void scan_block_k(
    const int* __restrict__ counts, int* __restrict__ row_start,
    int* __restrict__ blocksums, int n)
{
    __shared__ int sdata[256];
    int tid = threadIdx.x;
    int base = blockIdx.x * 1024 + tid * 4;
    int v[4]; int s = 0;
#pragma unroll
    for (int j = 0; j < 4; ++j) {
        v[j] = (base + j < n) ? counts[base + j] : 0;
        s += v[j];
    }
    sdata[tid] = s;
    __syncthreads();
    for (int off = 1; off < 256; off <<= 1) {
        int t = (tid >= off) ? sdata[tid - off] : 0;
        __syncthreads();
        sdata[tid] += t;
        __syncthreads();
    }
    int run = sdata[tid] - s;
#pragma unroll
    for (int j = 0; j < 4; ++j) {
        if (base + j < n) row_start[base + j] = run;
        run += v[j];
    }
    if (tid == 255) blocksums[blockIdx.x] = sdata[255];
}

__global__ __launch_bounds__(256) void scan_add_k(
    int* __restrict__ row_start, int* __restrict__ cursor,
    const int* __restrict__ blocksums, int n, int nb)
{
    __shared__ int red[2];
    int tid = threadIdx.x;
    if (tid < 128) {
        int v = (tid < (int)blockIdx.x && tid < nb) ? blocksums[tid] : 0;
#pragma unroll
        for (int o = 1; o < 64; o <<= 1) v += __shfl_xor(v, o, 64);
        if ((tid & 63) == 0) red[tid >> 6] = v;
    }
    __syncthreads();
    int off = red[0] + red[1];

    int base = blockIdx.x * 1024 + tid * 4;
#pragma unroll
    for (int j = 0; j < 4; ++j) {
        int idx = base + j;
        if (idx < n) {
            int v = row_start[idx] + off;
            row_start[idx] = v;
            cursor[idx] = v;
        }
    }
}

// ------- fused scatter + gate logit + sigmoid; gate packed into pe.y -------------
__global__ void scatter_payload_k(
    const int* __restrict__ ei, const int* __restrict__ deprel,
    const int* __restrict__ deparc, int* __restrict__ cursor,
    const float* __restrict__ xg,
    const float* __restrict__ bg_in, const float* __restrict__ bg_out,
    int2* __restrict__ pe, int* __restrict__ rel_arr, int E)
{
    int e = blockIdx.x * 256 + threadIdx.x;
    if (e >= E) return;
    int tgt = ei[E + e];
    int src = ei[e];
    int t   = deparc[e];
    int rel = deprel[e];
    int pos = atomicAdd(&cursor[tgt], 1);
    float gl = xg[(size_t)src * 4 + t];
    if (t == 0)      gl += bg_in[rel];
    else if (t == 1) gl += bg_out[rel];
    float g = 1.f / (1.f + __expf(-gl));
    pe[pos]      = make_int2(src | (t << 20), __builtin_bit_cast(int, g));
    rel_arr[pos] = rel;
}

// ---------------- fused aggregate(S) + GEMM(K=512) + residual + relu -------------
// Per-edge scalar-uniform fetch/consume: readlane -> SGPR, saddr gather,
// uniform t-branch (one body: 2 unpack + 2 FMA).
#define RFETCH(idx, PS, GS, V) do {                                                 \
    PS = __builtin_amdgcn_readlane(pgx, (idx));                                     \
    GS = __builtin_amdgcn_readlane(pgy, (idx));                                     \
    V  = xbu[((size_t)((unsigned)(PS) & 0xFFFFFu) << 6) + lane];                    \
} while (0)

#define RCONSUME(PS, GS, V) do {                                                    \
    float g_  = __builtin_bit_cast(float, (GS));                                    \
    float lo_ = __builtin_bit_cast(float, (V) << 16);                               \
    float hi_ = __builtin_bit_cast(float, (V) & 0xffff0000u);                       \
    int t_ = (int)((unsigned)(PS) >> 20);                                           \
    if (t_ == 0)      { a00 += lo_ * g_; a01 += hi_ * g_; }                         \
    else if (t_ == 1) { a10 += lo_ * g_; a11 += hi_ * g_; }                         \
    else if (t_ == 2) { a20 += lo_ * g_; a21 += hi_ * g_; }                         \
    else              { a30 += lo_ * g_; a31 += hi_ * g_; }                         \
} while (0)

__global__ __launch_bounds__(512, 8) void fused_agg_gemm_k(
    const unsigned short* __restrict__ xb,
    const unsigned short* __restrict__ wcatT,
    const int2* __restrict__ pe, const int* __restrict__ rel_arr,
    const int* __restrict__ row_start, const int* __restrict__ counts,
    const float* __restrict__ b_in, const float* __restrict__ b_out,
    float* __restrict__ Sb, float* __restrict__ out,
    const int* __restrict__ bnz, int N)
{
    // S-tile: 32 rows x 512 k, bf16, row stride 1024 B, XOR-swizzled. 32 KB.
    __shared__ __align__(16) unsigned char smem[32 * 1024];

    int tid  = threadIdx.x;
    int wave = tid >> 6, lane = tid & 63;
    int rowb = blockIdx.x * 32;
    int bz = (*bnz == 0);
    const unsigned* __restrict__ xbu = (const unsigned*)xb;  // row = 64 dwords

    // ---------------- phase 1: gather-aggregate S into LDS ----------------
    // One wave per row; lane covers d = 2*lane, 2*lane+1.
    for (int pass = 0; pass < 4; ++pass) {
        int r = pass * 8 + wave;   // row in tile 0..31
        int n = rowb + r;
        bool valid = n < N;
        int start = 0, cnt = 0;
        if (valid) { start = row_start[n]; cnt = counts[n]; }

        float a00 = 0.f, a01 = 0.f;
        float a10 = 0.f, a11 = 0.f;
        float a20 = 0.f, a21 = 0.f;
        float a30 = 0.f, a31 = 0.f;
        float ab0 = 0.f, ab1 = 0.f;

        if (bz) {
            // fast path: depth-4 pipeline, all edge scalars wave-uniform
            for (int base2 = 0; base2 < cnt; base2 += 64) {
                int m = min(cnt - base2, 64);
                int pgx = 0, pgy = 0;
                if (lane < m) {
                    int2 pg = pe[start + base2 + lane];
                    pgx = pg.x; pgy = pg.y;
                }
                int p0 = 0, p1 = 0, p2 = 0, p3 = 0;
                int q0 = 0, q1 = 0, q2 = 0, q3 = 0;
                unsigned v0 = 0, v1 = 0, v2 = 0, v3 = 0;
                if (0 < m) RFETCH(0, p0, q0, v0);
                if (1 < m) RFETCH(1, p1, q1, v1);
                if (2 < m) RFETCH(2, p2, q2, v2);
                if (3 < m) RFETCH(3, p3, q3, v3);

                for (int j = 0; j < m; j += 4) {
                    RCONSUME(p0, q0, v0);
                    if (j + 4 < m) RFETCH(j + 4, p0, q0, v0);
                    if (j + 1 < m) {
                        RCONSUME(p1, q1, v1);
                        if (j + 5 < m) RFETCH(j + 5, p1, q1, v1);
                    }
                    if (j + 2 < m) {
                        RCONSUME(p2, q2, v2);
                        if (j + 6 < m) RFETCH(j + 6, p2, q2, v2);
                    }
                    if (j + 3 < m) {
                        RCONSUME(p3, q3, v3);
                        if (j + 7 < m) RFETCH(j + 7, p3, q3, v3);
                    }
                }
            }
        } else {
            // exact generic path: also accumulate gathered bias rows (output space)
            for (int base2 = 0; base2 < cnt; base2 += 64) {
                int m = min(cnt - base2, 64);
                int pgx = 0, pgy = 0, prl = 0;
                if (lane < m) {
                    int2 pg = pe[start + base2 + lane];
                    pgx = pg.x; pgy = pg.y;
                    prl = rel_arr[start + base2 + lane];
                }
                for (int j = 0; j < m; ++j) {
                    int ps = __builtin_amdgcn_readlane(pgx, j);
                    int gs = __builtin_amdgcn_readlane(pgy, j);
                    int rl = __builtin_amdgcn_readlane(prl, j);
                    float g_ = __builtin_bit_cast(float, gs);
                    unsigned v = xbu[((size_t)((unsigned)ps & 0xFFFFFu) << 6) + lane];
                    float lo_ = __builtin_bit_cast(float, v << 16);
                    float hi_ = __builtin_bit_cast(float, v & 0xffff0000u);
                    int t_ = (int)((unsigned)ps >> 20);
                    if (t_ == 0) {
                        a00 += lo_ * g_; a01 += hi_ * g_;
                        float2 bb = *(const float2*)(b_in + (size_t)rl * DIM + lane * 2);
                        ab0 += g_ * bb.x; ab1 += g_ * bb.y;
                    } else if (t_ == 1) {
                        a10 += lo_ * g_; a11 += hi_ * g_;
                        float2 bb = *(const float2*)(b_out + (size_t)rl * DIM + lane * 2);
                        ab0 += g_ * bb.x; ab1 += g_ * bb.y;
                    } else if (t_ == 2) { a20 += lo_ * g_; a21 += hi_ * g_; }
                    else                { a30 += lo_ * g_; a31 += hi_ * g_; }
                }
            }
        }

        if (valid) {
            // S row layout: k = t*128 + d; lane covers d=2l,2l+1 per branch.
            // swizzle: byteoff ^= (row&7)<<4 (bits 4-6; 4B alignment preserved)
            unsigned sw = (unsigned)((r & 7) << 4);
            unsigned rb = (unsigned)r * 1024;
            *(unsigned*)(&smem[rb + ((  0u + lane * 4u) ^ sw)]) = f2bf(a00) | (f2bf(a01) << 16);
            *(unsigned*)(&smem[rb + ((256u + lane * 4u) ^ sw)]) = f2bf(a10) | (f2bf(a11) << 16);
            *(unsigned*)(&smem[rb + ((512u + lane * 4u) ^ sw)]) = f2bf(a20) | (f2bf(a21) << 16);
            *(unsigned*)(&smem[rb + ((768u + lane * 4u) ^ sw)]) = f2bf(a30) | (f2bf(a31) << 16);
            if (!bz)
                *(float2*)(Sb + (size_t)n * DIM + lane * 2) = make_float2(ab0, ab1);
        }
    }

    __syncthreads();

    // ---------------- phase 2: S_tile @ Wcat (K=512) ----------------
    // A-operand layout (proven in gemm_xv_k): col on lane&15, k = quad*8+j.
    int quad = lane >> 4, l15 = lane & 15;
    int colb = wave * 16 + quad * 4;
    const unsigned short* wc = wcatT + (size_t)(wave * 16 + l15) * 512;

    floatx4 ac0 = {0.f, 0.f, 0.f, 0.f}, ac1 = ac0;
    unsigned swl = (unsigned)((l15 & 7) << 4);
#pragma unroll
    for (int kt = 0; kt < 16; ++kt) {
        short8 wf = *(const short8*)(wc + kt * 32 + quad * 8);
        unsigned bo = ((unsigned)(kt * 64 + quad * 16)) ^ swl;
        short8 x0 = *(const short8*)(&smem[(unsigned)(     l15) * 1024 + bo]);
        short8 x1 = *(const short8*)(&smem[(unsigned)(16 + l15) * 1024 + bo]);
        ac0 = __builtin_amdgcn_mfma_f32_16x16x32_bf16(wf, x0, ac0, 0, 0, 0);
        ac1 = __builtin_amdgcn_mfma_f32_16x16x32_bf16(wf, x1, ac1, 0, 0, 0);
    }

    // epilogue: + xb residual (+ Sb bias term if !bz), relu, store.
    // D layout (from gemm_xv_k): row = l15 (+16*s), col = colb + reg.
#define EPI(AC, S) do {                                                             \
    int row = rowb + (S) * 16 + l15;                                                \
    if (row < N) {                                                                  \
        uint2 ix = *(const uint2*)(xb + (size_t)row * DIM + colb);                  \
        float4 o;                                                                   \
        o.x = (AC)[0] + bf2f(ix.x & 0xffffu);                                       \
        o.y = (AC)[1] + bf2f(ix.x >> 16);                                           \
        o.z = (AC)[2] + bf2f(ix.y & 0xffffu);                                       \
        o.w = (AC)[3] + bf2f(ix.y >> 16);                                           \
        if (!bz) {                                                                  \
            float4 sb = *(const float4*)(Sb + (size_t)row * DIM + colb);            \
            o.x += sb.x; o.y += sb.y; o.z += sb.z; o.w += sb.w;                     \
        }                                                                           \
        o.x = fmaxf(o.x, 0.f); o.y = fmaxf(o.y, 0.f);                               \
        o.z = fmaxf(o.z, 0.f); o.w = fmaxf(o.w, 0.f);                               \
        *(float4*)(out + (size_t)row * DIM + colb) = o;                             \
    }                                                                               \
} while (0)

    EPI(ac0, 0);
    EPI(ac1, 1);
#undef EPI
}

extern "C" void kernel_launch(void* const* d_in, const int* in_sizes, int n_in,
                              void* d_out, int out_size, void* d_ws, size_t ws_size,
                              hipStream_t stream)
{
    const float* inp    = (const float*)d_in[0];
    const int*   deprel = (const int*)d_in[1];
    const int*   deparc = (const int*)d_in[2];
    const int*   ei     = (const int*)d_in[3];
    const float* Vin    = (const float*)d_in[4];
    const float* b_in   = (const float*)d_in[5];
    const float* gin    = (const float*)d_in[6];
    const float* bg_in  = (const float*)d_in[7];
    const float* Vout   = (const float*)d_in[8];
    const float* b_out  = (const float*)d_in[9];
    const float* gout   = (const float*)d_in[10];
    const float* bg_out = (const float*)d_in[11];
    const float* Wself  = (const float*)d_in[12];
    const float* gself  = (const float*)d_in[13];
    const float* Wnorel = (const float*)d_in[14];
    const float* gnorel = (const float*)d_in[15];
    float*       out    = (float*)d_out;

    const int N = in_sizes[0] / DIM;   // 100000
    const int E = in_sizes[1];         // 400000
    const long long nbe = (long long)in_sizes[5];  // R*128

    char* ws = (char*)d_ws;
    size_t off = 0;
    auto alloc = [&](size_t bytes) -> void* {
        void* p = ws + off;
        off = (off + bytes + 255) & ~(size_t)255;
        return p;
    };
    float*          xg        = (float*)alloc((size_t)N * 4 * 4);
    int*            counts    = (int*)alloc((size_t)N * 4);   // |
    int*            bnz       = (int*)alloc(256);             // | one memset region
    int*            row_start = (int*)alloc((size_t)N * 4);
    int*            cursor    = (int*)alloc((size_t)N * 4);
    int2*           pe        = (int2*)alloc((size_t)E * 8);
    int*            rel_arr   = (int*)alloc((size_t)E * 4);
    int*            blocksums = (int*)alloc(128 * 4);
    unsigned short* xb        = (unsigned short*)alloc((size_t)N * DIM * 2); // 25.6 MB
    unsigned short* wcatT     = (unsigned short*)alloc((size_t)128 * 512 * 2); // 128 KB
    float*          Sb        = (float*)alloc((size_t)N * DIM * 4);          // 51.2 MB

    int nb_scan  = (N + 1023) / 1024;
    int nb_edge  = (E + 255) / 256;
    int nb_node4 = (N + 3) / 4;
    int nb_fused = (N + 31) / 32;

    // zero counts + bnz in one memset (adjacent in ws)
    size_t zlen = (size_t)((char*)bnz - (char*)counts) + 256;
    hipMemsetAsync(counts, 0, zlen, stream);

    conv_hist_k<<<nb_node4 + nb_edge + 256 + 128, 256, 0, stream>>>(
        inp, gin, gout, gself, gnorel, Vin, Vout, Wself, Wnorel,
        xb, xg, wcatT, ei, counts, b_in, b_out, bnz, nbe, N, E, nb_node4, nb_edge);

    scan_block_k<<<nb_scan, 256, 0, stream>>>(counts, row_start, blocksums, N);
    scan_add_k<<<nb_scan, 256, 0, stream>>>(row_start, cursor, blocksums, N, nb_scan);
    scatter_payload_k<<<nb_edge, 256, 0, stream>>>(ei, deprel, deparc, cursor,
                                                   xg, bg_in, bg_out, pe, rel_arr, E);

    fused_agg_gemm_k<<<nb_fused, 512, 0, stream>>>(
        xb, wcatT, pe, rel_arr, row_start, counts, b_in, b_out, Sb, out, bnz, N);
}

// Round 4
// 260.105 us; speedup vs baseline: 1.0389x; 1.0389x over previous
//
#include <hip/hip_runtime.h>

// SyntacticGCN on MI355X — fp32 in/out.
// v5: scalar-uniform control flow in the gather loop (readfirstlane hoisting).
//   S[n, t*128+d] = sum_{e:tgt=n,t_e=t} g_e * x[src_e, d]   (gather from 25.6MB xb)
//   out[n] = relu(inp[n] + S[n,:] @ Wcat)                    (one K=512 GEMM)
//
// v5 changes (post-mortem of v4: dur AND bank-conflicts unchanged after shfl
// removal => conflicts are phase-2 ds_reads (minor); VALUBusy 33% at ~6
// VALU/edge => compiler can't prove tid>>6 uniform, so cnt/m/guards compile
// as exec-mask vector ops — divergent-control overhead dominates):
//   - fused: start/cnt/bz hoisted to SGPR via __builtin_amdgcn_readfirstlane
//     -> all phase-1 loops/guards become scalar (s_cmp/s_cbranch), per-edge
//     cost ~4 VALU + ~6 SALU.
//   - conv: 16 nodes/wave (lane=(quad,node)), fp32 partial dots per lane,
//     cross-quad reduce = 2 shfl steps per 16 nodes (was 24 bpermute/node).
//   - scatter: payload packed to one int4 (src|t, gate, rel) -> 1 random
//     store line per edge (was 2).
//
// Pipeline (6 dispatches): memset | conv_hist_k | scan_block_k | scan_add_k |
//   scatter_payload_k | fused_agg_gemm_k.

typedef __attribute__((ext_vector_type(8))) short short8;
typedef __attribute__((ext_vector_type(4))) float floatx4;

#define DIM 128

static __device__ __forceinline__ float bf2f(unsigned int u16bits) {
    unsigned int x = u16bits << 16;
    return __builtin_bit_cast(float, x);
}
static __device__ __forceinline__ unsigned int f2bf(float f) {
    unsigned int x = __builtin_bit_cast(unsigned int, f);
    return (x + 0x7fffu + ((x >> 16) & 1u)) >> 16;
}

// ------- fused: conv+gate (node blocks) | hist | zcheck | weight-convert ---------
__global__ __launch_bounds__(256) void conv_hist_k(
    const float* __restrict__ inp,
    const float* __restrict__ gin,  const float* __restrict__ gout,
    const float* __restrict__ gself, const float* __restrict__ gnorel,
    const float* __restrict__ Vin, const float* __restrict__ Vout,
    const float* __restrict__ Wself, const float* __restrict__ Wnorel,
    unsigned short* __restrict__ xb, float* __restrict__ xg,
    unsigned short* __restrict__ wcatT,
    const int* __restrict__ ei, int* __restrict__ counts,
    const float* __restrict__ b_in, const float* __restrict__ b_out,
    int* __restrict__ bnz, long long nbe,
    int N, int E, int nb_conv, int nb_edge)
{
    int bx = (int)blockIdx.x;
    if (bx >= nb_conv + nb_edge + 256) {
        // weight convert: wcatT[c][k] = bf16(W_t[d][c]), k = t*128+d. 128 blocks.
        int gid = (bx - nb_conv - nb_edge - 256) * 256 + threadIdx.x; // 32768
        int k = gid >> 6;            // 0..511
        int c2 = (gid & 63) * 2;     // 0,2,..,126
        int t = k >> 7, d = k & 127;
        const float* Wt = (t == 0) ? Vin : (t == 1) ? Vout : (t == 2) ? Wself : Wnorel;
        float2 w = *(const float2*)(Wt + (size_t)d * DIM + c2);
        wcatT[(size_t)c2 * 512 + k]       = (unsigned short)f2bf(w.x);
        wcatT[(size_t)(c2 + 1) * 512 + k] = (unsigned short)f2bf(w.y);
        return;
    }
    if (bx >= nb_conv + nb_edge) {
        // sampler: 256 blocks x 256 threads, strided over the bias tables
        long long tid = (long long)(bx - nb_conv - nb_edge) * 256 + threadIdx.x;
        long long stride = nbe / 65536;
        long long i = tid * stride;
        if (i < nbe && (b_in[i] != 0.f || b_out[i] != 0.f)) *bnz = 1;
        return;
    }
    if (bx >= nb_conv) {
        int e = (bx - nb_conv) * 256 + threadIdx.x;
        if (e < E) atomicAdd(&counts[ei[E + e]], 1);
        return;
    }
    // node-conv: 4 waves x 16 nodes = 64 nodes per block.
    // Lane (q, l15): node = l15, covers k = kt*32 + q*8 .. +8 for kt=0..3.
    int wv   = threadIdx.x >> 6;
    int lane = threadIdx.x & 63;
    int q = lane >> 4, l15 = lane & 15;
    int n = bx * 64 + wv * 16 + l15;
    int rowc = n < N ? n : N - 1;
    const float* xr = inp + (size_t)rowc * DIM;

    float4 acc = make_float4(0.f, 0.f, 0.f, 0.f);
    unsigned xpk[16];
#pragma unroll
    for (int kt = 0; kt < 4; ++kt) {
        int ko = kt * 32 + q * 8;
        float4 xa = *(const float4*)(xr + ko);
        float4 xc = *(const float4*)(xr + ko + 4);
        float4 ga, gb;
        ga = *(const float4*)(gin + ko);    gb = *(const float4*)(gin + ko + 4);
        acc.x += xa.x*ga.x + xa.y*ga.y + xa.z*ga.z + xa.w*ga.w
               + xc.x*gb.x + xc.y*gb.y + xc.z*gb.z + xc.w*gb.w;
        ga = *(const float4*)(gout + ko);   gb = *(const float4*)(gout + ko + 4);
        acc.y += xa.x*ga.x + xa.y*ga.y + xa.z*ga.z + xa.w*ga.w
               + xc.x*gb.x + xc.y*gb.y + xc.z*gb.z + xc.w*gb.w;
        ga = *(const float4*)(gself + ko);  gb = *(const float4*)(gself + ko + 4);
        acc.z += xa.x*ga.x + xa.y*ga.y + xa.z*ga.z + xa.w*ga.w
               + xc.x*gb.x + xc.y*gb.y + xc.z*gb.z + xc.w*gb.w;
        ga = *(const float4*)(gnorel + ko); gb = *(const float4*)(gnorel + ko + 4);
        acc.w += xa.x*ga.x + xa.y*ga.y + xa.z*ga.z + xa.w*ga.w
               + xc.x*gb.x + xc.y*gb.y + xc.z*gb.z + xc.w*gb.w;
        xpk[kt*4+0] = f2bf(xa.x) | (f2bf(xa.y) << 16);
        xpk[kt*4+1] = f2bf(xa.z) | (f2bf(xa.w) << 16);
        xpk[kt*4+2] = f2bf(xc.x) | (f2bf(xc.y) << 16);
        xpk[kt*4+3] = f2bf(xc.z) | (f2bf(xc.w) << 16);
    }
    if (n < N) {
#pragma unroll
        for (int kt = 0; kt < 4; ++kt) {
            uint4 o = make_uint4(xpk[kt*4], xpk[kt*4+1], xpk[kt*4+2], xpk[kt*4+3]);
            *(uint4*)(xb + (size_t)n * DIM + kt * 32 + q * 8) = o;
        }
    }
    // reduce across q (lane^16, lane^32): 8 shuffles per 16 nodes total
#pragma unroll
    for (int off = 16; off < 64; off <<= 1) {
        acc.x += __shfl_xor(acc.x, off, 64);
        acc.y += __shfl_xor(acc.y, off, 64);
        acc.z += __shfl_xor(acc.z, off, 64);
        acc.w += __shfl_xor(acc.w, off, 64);
    }
    if (q == 0 && n < N) *(float4*)(xg + (size_t)n * 4) = acc;
}

// ---------------- CSR scan (2 kernels, unchanged) ----------------
__global__ __launch_bounds__(256) void scan_block_k(
    const int* __restrict__ counts, int* __restrict__ row_start,
    int* __restrict__ blocksums, int n)
{
    __shared__ int sdata[256];
    int tid = threadIdx.x;
    int base = blockIdx.x * 1024 + tid * 4;
    int v[4]; int s = 0;
#pragma unroll
    for (int j = 0; j < 4; ++j) {
        v[j] = (base + j < n) ? counts[base + j] : 0;
        s += v[j];
    }
    sdata[tid] = s;
    __syncthreads();
    for (int off = 1; off < 256; off <<= 1) {
        int t = (tid >= off) ? sdata[tid - off] : 0;
        __syncthreads();
        sdata[tid] += t;
        __syncthreads();
    }
    int run = sdata[tid] - s;
#pragma unroll
    for (int j = 0; j < 4; ++j) {
        if (base + j < n) row_start[base + j] = run;
        run += v[j];
    }
    if (tid == 255) blocksums[blockIdx.x] = sdata[255];
}

__global__ __launch_bounds__(256) void scan_add_k(
    int* __restrict__ row_start, int* __restrict__ cursor,
    const int* __restrict__ blocksums, int n, int nb)
{
    __shared__ int red[2];
    int tid = threadIdx.x;
    if (tid < 128) {
        int v = (tid < (int)blockIdx.x && tid < nb) ? blocksums[tid] : 0;
#pragma unroll
        for (int o = 1; o < 64; o <<= 1) v += __shfl_xor(v, o, 64);
        if ((tid & 63) == 0) red[tid >> 6] = v;
    }
    __syncthreads();
    int off = red[0] + red[1];

    int base = blockIdx.x * 1024 + tid * 4;
#pragma unroll
    for (int j = 0; j < 4; ++j) {
        int idx = base + j;
        if (idx < n) {
            int v = row_start[idx] + off;
            row_start[idx] = v;
            cursor[idx] = v;
        }
    }
}

// -- fused scatter + gate logit + sigmoid; payload = int4 (src|t, gate, rel) ------
__global__ void scatter_payload_k(
    const int* __restrict__ ei, const int* __restrict__ deprel,
    const int* __restrict__ deparc, int* __restrict__ cursor,
    const float* __restrict__ xg,
    const float* __restrict__ bg_in, const float* __restrict__ bg_out,
    int4* __restrict__ pe, int E)
{
    int e = blockIdx.x * 256 + threadIdx.x;
    if (e >= E) return;
    int tgt = ei[E + e];
    int src = ei[e];
    int t   = deparc[e];
    int rel = deprel[e];
    int pos = atomicAdd(&cursor[tgt], 1);
    float gl = xg[(size_t)src * 4 + t];
    if (t == 0)      gl += bg_in[rel];
    else if (t == 1) gl += bg_out[rel];
    float g = 1.f / (1.f + __expf(-gl));
    pe[pos] = make_int4(src | (t << 20), __builtin_bit_cast(int, g), rel, 0);
}

// ---------------- fused aggregate(S) + GEMM(K=512) + residual + relu -------------
// Per-edge scalar-uniform fetch/consume: readlane -> SGPR, saddr gather,
// uniform scalar t-branch (one body: 2 unpack + 2 FMA). All loop bounds SGPR.
#define RFETCH(idx, PS, GS, V) do {                                                 \
    PS = __builtin_amdgcn_readlane(pgx, (idx));                                     \
    GS = __builtin_amdgcn_readlane(pgy, (idx));                                     \
    V  = xbu[((size_t)((unsigned)(PS) & 0xFFFFFu) << 6) + lane];                    \
} while (0)

#define RCONSUME(PS, GS, V) do {                                                    \
    float g_  = __builtin_bit_cast(float, (GS));                                    \
    float lo_ = __builtin_bit_cast(float, (V) << 16);                               \
    float hi_ = __builtin_bit_cast(float, (V) & 0xffff0000u);                       \
    int t_ = (int)((unsigned)(PS) >> 20);                                           \
    if (t_ == 0)      { a00 += lo_ * g_; a01 += hi_ * g_; }                         \
    else if (t_ == 1) { a10 += lo_ * g_; a11 += hi_ * g_; }                         \
    else if (t_ == 2) { a20 += lo_ * g_; a21 += hi_ * g_; }                         \
    else              { a30 += lo_ * g_; a31 += hi_ * g_; }                         \
} while (0)

__global__ __launch_bounds__(512, 8) void fused_agg_gemm_k(
    const unsigned short* __restrict__ xb,
    const unsigned short* __restrict__ wcatT,
    const int4* __restrict__ pe,
    const int* __restrict__ row_start, const int* __restrict__ counts,
    const float* __restrict__ b_in, const float* __restrict__ b_out,
    float* __restrict__ Sb, float* __restrict__ out,
    const int* __restrict__ bnz, int N)
{
    // S-tile: 32 rows x 512 k, bf16, row stride 1024 B, XOR-swizzled. 32 KB.
    __shared__ __align__(16) unsigned char smem[32 * 1024];

    int tid  = threadIdx.x;
    int wave = tid >> 6, lane = tid & 63;
    int rowb = blockIdx.x * 32;
    int bz = __builtin_amdgcn_readfirstlane((*bnz == 0) ? 1 : 0);
    const unsigned* __restrict__ xbu = (const unsigned*)xb;  // row = 64 dwords
    const int2* __restrict__ pe2 = (const int2*)pe;          // .xy of each int4

    // ---------------- phase 1: gather-aggregate S into LDS ----------------
    // One wave per row; lane covers d = 2*lane, 2*lane+1.
    for (int pass = 0; pass < 4; ++pass) {
        int r = pass * 8 + wave;   // row in tile 0..31
        int n = rowb + r;
        bool valid = n < N;
        int start = 0, cnt = 0;
        if (valid) { start = row_start[n]; cnt = counts[n]; }
        start = __builtin_amdgcn_readfirstlane(start);  // wave-uniform -> SGPR:
        cnt   = __builtin_amdgcn_readfirstlane(cnt);    // scalar loops/guards below

        float a00 = 0.f, a01 = 0.f;
        float a10 = 0.f, a11 = 0.f;
        float a20 = 0.f, a21 = 0.f;
        float a30 = 0.f, a31 = 0.f;
        float ab0 = 0.f, ab1 = 0.f;

        if (bz) {
            // fast path: depth-4 pipeline, all edge scalars in SGPRs
            for (int base2 = 0; base2 < cnt; base2 += 64) {
                int m = min(cnt - base2, 64);
                int pgx = 0, pgy = 0;
                if (lane < m) {
                    int2 pg = pe2[(size_t)(start + base2 + lane) * 2];
                    pgx = pg.x; pgy = pg.y;
                }
                int p0 = 0, p1 = 0, p2 = 0, p3 = 0;
                int q0 = 0, q1 = 0, q2 = 0, q3 = 0;
                unsigned v0 = 0, v1 = 0, v2 = 0, v3 = 0;
                if (0 < m) RFETCH(0, p0, q0, v0);
                if (1 < m) RFETCH(1, p1, q1, v1);
                if (2 < m) RFETCH(2, p2, q2, v2);
                if (3 < m) RFETCH(3, p3, q3, v3);

                for (int j = 0; j < m; j += 4) {
                    RCONSUME(p0, q0, v0);
                    if (j + 4 < m) RFETCH(j + 4, p0, q0, v0);
                    if (j + 1 < m) {
                        RCONSUME(p1, q1, v1);
                        if (j + 5 < m) RFETCH(j + 5, p1, q1, v1);
                    }
                    if (j + 2 < m) {
                        RCONSUME(p2, q2, v2);
                        if (j + 6 < m) RFETCH(j + 6, p2, q2, v2);
                    }
                    if (j + 3 < m) {
                        RCONSUME(p3, q3, v3);
                        if (j + 7 < m) RFETCH(j + 7, p3, q3, v3);
                    }
                }
            }
        } else {
            // exact generic path: also accumulate gathered bias rows (output space)
            for (int base2 = 0; base2 < cnt; base2 += 64) {
                int m = min(cnt - base2, 64);
                int pgx = 0, pgy = 0, prl = 0;
                if (lane < m) {
                    int4 pg = pe[start + base2 + lane];
                    pgx = pg.x; pgy = pg.y; prl = pg.z;
                }
                for (int j = 0; j < m; ++j) {
                    int ps = __builtin_amdgcn_readlane(pgx, j);
                    int gs = __builtin_amdgcn_readlane(pgy, j);
                    int rl = __builtin_amdgcn_readlane(prl, j);
                    float g_ = __builtin_bit_cast(float, gs);
                    unsigned v = xbu[((size_t)((unsigned)ps & 0xFFFFFu) << 6) + lane];
                    float lo_ = __builtin_bit_cast(float, v << 16);
                    float hi_ = __builtin_bit_cast(float, v & 0xffff0000u);
                    int t_ = (int)((unsigned)ps >> 20);
                    if (t_ == 0) {
                        a00 += lo_ * g_; a01 += hi_ * g_;
                        float2 bb = *(const float2*)(b_in + (size_t)rl * DIM + lane * 2);
                        ab0 += g_ * bb.x; ab1 += g_ * bb.y;
                    } else if (t_ == 1) {
                        a10 += lo_ * g_; a11 += hi_ * g_;
                        float2 bb = *(const float2*)(b_out + (size_t)rl * DIM + lane * 2);
                        ab0 += g_ * bb.x; ab1 += g_ * bb.y;
                    } else if (t_ == 2) { a20 += lo_ * g_; a21 += hi_ * g_; }
                    else                { a30 += lo_ * g_; a31 += hi_ * g_; }
                }
            }
        }

        if (valid) {
            // S row layout: k = t*128 + d; lane covers d=2l,2l+1 per branch.
            // swizzle: byteoff ^= (row&7)<<4 (bits 4-6; 4B alignment preserved)
            unsigned sw = (unsigned)((r & 7) << 4);
            unsigned rb = (unsigned)r * 1024;
            *(unsigned*)(&smem[rb + ((  0u + lane * 4u) ^ sw)]) = f2bf(a00) | (f2bf(a01) << 16);
            *(unsigned*)(&smem[rb + ((256u + lane * 4u) ^ sw)]) = f2bf(a10) | (f2bf(a11) << 16);
            *(unsigned*)(&smem[rb + ((512u + lane * 4u) ^ sw)]) = f2bf(a20) | (f2bf(a21) << 16);
            *(unsigned*)(&smem[rb + ((768u + lane * 4u) ^ sw)]) = f2bf(a30) | (f2bf(a31) << 16);
            if (!bz)
                *(float2*)(Sb + (size_t)n * DIM + lane * 2) = make_float2(ab0, ab1);
        }
    }

    __syncthreads();

    // ---------------- phase 2: S_tile @ Wcat (K=512) ----------------
    // A-operand layout (proven in gemm_xv_k): col on lane&15, k = quad*8+j.
    int quad = lane >> 4, l15 = lane & 15;
    int colb = wave * 16 + quad * 4;
    const unsigned short* wc = wcatT + (size_t)(wave * 16 + l15) * 512;

    floatx4 ac0 = {0.f, 0.f, 0.f, 0.f}, ac1 = ac0;
    unsigned swl = (unsigned)((l15 & 7) << 4);
#pragma unroll
    for (int kt = 0; kt < 16; ++kt) {
        short8 wf = *(const short8*)(wc + kt * 32 + quad * 8);
        unsigned bo = ((unsigned)(kt * 64 + quad * 16)) ^ swl;
        short8 x0 = *(const short8*)(&smem[(unsigned)(     l15) * 1024 + bo]);
        short8 x1 = *(const short8*)(&smem[(unsigned)(16 + l15) * 1024 + bo]);
        ac0 = __builtin_amdgcn_mfma_f32_16x16x32_bf16(wf, x0, ac0, 0, 0, 0);
        ac1 = __builtin_amdgcn_mfma_f32_16x16x32_bf16(wf, x1, ac1, 0, 0, 0);
    }

    // epilogue: + xb residual (+ Sb bias term if !bz), relu, store.
    // D layout (from gemm_xv_k): row = l15 (+16*s), col = colb + reg.
#define EPI(AC, S) do {                                                             \
    int row = rowb + (S) * 16 + l15;                                                \
    if (row < N) {                                                                  \
        uint2 ix = *(const uint2*)(xb + (size_t)row * DIM + colb);                  \
        float4 o;                                                                   \
        o.x = (AC)[0] + bf2f(ix.x & 0xffffu);                                       \
        o.y = (AC)[1] + bf2f(ix.x >> 16);                                           \
        o.z = (AC)[2] + bf2f(ix.y & 0xffffu);                                       \
        o.w = (AC)[3] + bf2f(ix.y >> 16);                                           \
        if (!bz) {                                                                  \
            float4 sb = *(const float4*)(Sb + (size_t)row * DIM + colb);            \
            o.x += sb.x; o.y += sb.y; o.z += sb.z; o.w += sb.w;                     \
        }                                                                           \
        o.x = fmaxf(o.x, 0.f); o.y = fmaxf(o.y, 0.f);                               \
        o.z = fmaxf(o.z, 0.f); o.w = fmaxf(o.w, 0.f);                               \
        *(float4*)(out + (size_t)row * DIM + colb) = o;                             \
    }                                                                               \
} while (0)

    EPI(ac0, 0);
    EPI(ac1, 1);
#undef EPI
}

extern "C" void kernel_launch(void* const* d_in, const int* in_sizes, int n_in,
                              void* d_out, int out_size, void* d_ws, size_t ws_size,
                              hipStream_t stream)
{
    const float* inp    = (const float*)d_in[0];
    const int*   deprel = (const int*)d_in[1];
    const int*   deparc = (const int*)d_in[2];
    const int*   ei     = (const int*)d_in[3];
    const float* Vin    = (const float*)d_in[4];
    const float* b_in   = (const float*)d_in[5];
    const float* gin    = (const float*)d_in[6];
    const float* bg_in  = (const float*)d_in[7];
    const float* Vout   = (const float*)d_in[8];
    const float* b_out  = (const float*)d_in[9];
    const float* gout   = (const float*)d_in[10];
    const float* bg_out = (const float*)d_in[11];
    const float* Wself  = (const float*)d_in[12];
    const float* gself  = (const float*)d_in[13];
    const float* Wnorel = (const float*)d_in[14];
    const float* gnorel = (const float*)d_in[15];
    float*       out    = (float*)d_out;

    const int N = in_sizes[0] / DIM;   // 100000
    const int E = in_sizes[1];         // 400000
    const long long nbe = (long long)in_sizes[5];  // R*128

    char* ws = (char*)d_ws;
    size_t off = 0;
    auto alloc = [&](size_t bytes) -> void* {
        void* p = ws + off;
        off = (off + bytes + 255) & ~(size_t)255;
        return p;
    };
    float*          xg        = (float*)alloc((size_t)N * 4 * 4);
    int*            counts    = (int*)alloc((size_t)N * 4);   // |
    int*            bnz       = (int*)alloc(256);             // | one memset region
    int*            row_start = (int*)alloc((size_t)N * 4);
    int*            cursor    = (int*)alloc((size_t)N * 4);
    int4*           pe        = (int4*)alloc((size_t)E * 16);
    int*            blocksums = (int*)alloc(128 * 4);
    unsigned short* xb        = (unsigned short*)alloc((size_t)N * DIM * 2); // 25.6 MB
    unsigned short* wcatT     = (unsigned short*)alloc((size_t)128 * 512 * 2); // 128 KB
    float*          Sb        = (float*)alloc((size_t)N * DIM * 4);          // 51.2 MB

    int nb_scan  = (N + 1023) / 1024;
    int nb_edge  = (E + 255) / 256;
    int nb_node  = (N + 63) / 64;
    int nb_fused = (N + 31) / 32;

    // zero counts + bnz in one memset (adjacent in ws)
    size_t zlen = (size_t)((char*)bnz - (char*)counts) + 256;
    hipMemsetAsync(counts, 0, zlen, stream);

    conv_hist_k<<<nb_node + nb_edge + 256 + 128, 256, 0, stream>>>(
        inp, gin, gout, gself, gnorel, Vin, Vout, Wself, Wnorel,
        xb, xg, wcatT, ei, counts, b_in, b_out, bnz, nbe, N, E, nb_node, nb_edge);

    scan_block_k<<<nb_scan, 256, 0, stream>>>(counts, row_start, blocksums, N);
    scan_add_k<<<nb_scan, 256, 0, stream>>>(row_start, cursor, blocksums, N, nb_scan);
    scatter_payload_k<<<nb_edge, 256, 0, stream>>>(ei, deprel, deparc, cursor,
                                                   xg, bg_in, bg_out, pe, E);

    fused_agg_gemm_k<<<nb_fused, 512, 0, stream>>>(
        xb, wcatT, pe, row_start, counts, b_in, b_out, Sb, out, bnz, N);
}